// Round 1
// baseline (210.372 us; speedup 1.0000x reference)
//
#include <hip/hip_runtime.h>
#include <math.h>

#define N 4096
#define C 512
#define EMB 38
#define HEADS 4
#define HID 64
#define F1 256       // HEADS*HID
#define MAXN 128     // max neighbors per row (p=0.01 -> mean 41, >13 sigma headroom)
#define RPB 8        // rows per block in gemms

__device__ __forceinline__ float wr_sum(float v) {
#pragma unroll
    for (int o = 32; o > 0; o >>= 1) v += __shfl_xor(v, o);
    return v;
}
__device__ __forceinline__ float wr_max(float v) {
#pragma unroll
    for (int o = 32; o > 0; o >>= 1) v = fmaxf(v, __shfl_xor(v, o));
    return v;
}

// ---------------- PHASE 1 (fused): CSR build  ||  embed+GEMM1+attention dots ----------------
// build and gemm1 touch disjoint data (adj vs nf/W1) -> block-specialized fusion.
// Interleave 2 build blocks : 1 gemm1 block so HBM streaming (build) overlaps FMA (gemm1)
// across the whole dispatch instead of serializing two kernels.
__global__ __launch_bounds__(256) void k_phase1(const float* __restrict__ adj,
                                                int* __restrict__ cnt, int* __restrict__ idx,
                                                const float* __restrict__ nf, const float* __restrict__ W1,
                                                const float* __restrict__ asrc, const float* __restrict__ adst,
                                                float* __restrict__ h1, float* __restrict__ s1,
                                                float* __restrict__ d1) {
    int g = blockIdx.x / 3, r3 = blockIdx.x % 3;
    int tid = threadIdx.x;
    int wv = tid >> 6, lane = tid & 63;
    __shared__ int stage[4][MAXN];
    __shared__ float fs[RPB][8];
    __shared__ float xs[RPB][40];          // EMB=38 padded to 40, tail zeroed

    if (r3 != 2) {
        // ---- build path: block handles 4 adjacency rows, wave per row ----
        // full-row register load (16 float4 in flight), ballot compaction, LDS stage,
        // coalesced global write. (R8 lesson: depth-1 prefetch stuck at 2.2 TB/s.)
        int i = (2 * g + r3) * 4 + wv;
        const float4* row = (const float4*)(adj + (size_t)i * N);
        float4 v[16];
#pragma unroll
        for (int it = 0; it < 16; ++it) v[it] = row[it * 64 + lane];
        unsigned long long below = (1ull << lane) - 1;
        int base = 0;
#pragma unroll
        for (int it = 0; it < 16; ++it) {
            int col0 = 4 * (it * 64 + lane);
            float vals[4] = {v[it].x, v[it].y, v[it].z, v[it].w};
#pragma unroll
            for (int comp = 0; comp < 4; ++comp) {
                unsigned long long m = __ballot(vals[comp] > 0.f);
                if (vals[comp] > 0.f) {
                    int p = base + __popcll(m & below);
                    if (p < MAXN) stage[wv][p] = col0 + comp;
                }
                base += __popcll(m);
            }
        }
        int c = min(base, MAXN);
        __syncthreads();
        if (lane < c)      idx[i * MAXN + lane]      = stage[wv][lane];
        if (lane + 64 < c) idx[i * MAXN + lane + 64] = stage[wv][lane + 64];
        if (lane == 0) cnt[i] = c;
        return;
    }

    // ---- gemm1 path: 8 nodes/block, embed 38 features then 38->256 ----
    int n0 = g * RPB;
    if (tid < RPB * 8) fs[tid >> 3][tid & 7] = nf[(size_t)n0 * 8 + tid];
    if (tid < RPB * 2) xs[tid >> 1][38 + (tid & 1)] = 0.f;
    __syncthreads();
    {
        int r = tid & 7;
        int t = tid >> 3;               // 0..31
        const float* f = fs[r];
        for (int pass = 0; pass < 2; ++pass, t += 32) {
            if (t >= EMB) break;
            float val;
            if (t < 6) { int nt = min(max((int)f[0], 0), 5); val = (t == nt) ? 1.f : 0.f; }
            else if (t == 6) val = log1pf(f[1]);
            else if (t < 31) {
                int q = (t - 7) & 7, s = (t - 7) >> 3, m = q >> 1;
                float base = (s == 0) ? f[2] : (s == 1) ? f[3] : f[4] * 100.f;
                float div = expf((2.f * m) * (-logf(10000.f) / 8.f));
                float sc = base * div;
                val = (q & 1) ? cosf(sc) : sinf(sc);
            }
            else if (t < 36) { int role = min(max((int)f[5], 0), 4); val = (t - 31 == role) ? 1.f : 0.f; }
            else val = (t == 36) ? f[6] : f[7];
            xs[r][t] = val;
        }
    }
    __syncthreads();
    float acc[RPB];
#pragma unroll
    for (int r = 0; r < RPB; ++r) acc[r] = 0.f;
#pragma unroll
    for (int kk = 0; kk < 9; ++kk) {      // k = 0..35 via float4 LDS broadcast
        float w0 = W1[(4 * kk + 0) * F1 + tid];
        float w1 = W1[(4 * kk + 1) * F1 + tid];
        float w2 = W1[(4 * kk + 2) * F1 + tid];
        float w3 = W1[(4 * kk + 3) * F1 + tid];
#pragma unroll
        for (int r = 0; r < RPB; ++r) {
            float4 x = *(const float4*)&xs[r][4 * kk];
            acc[r] = fmaf(x.x, w0, fmaf(x.y, w1, fmaf(x.z, w2, fmaf(x.w, w3, acc[r]))));
        }
    }
#pragma unroll
    for (int k = 36; k < EMB; ++k) {      // tail
        float wvv = W1[k * F1 + tid];
#pragma unroll
        for (int r = 0; r < RPB; ++r) acc[r] = fmaf(xs[r][k], wvv, acc[r]);
    }
    int h = tid >> 6, ln = tid & 63;
    float av = asrc[tid], dv = adst[tid];
#pragma unroll
    for (int r = 0; r < RPB; ++r) {
        h1[(size_t)(n0 + r) * F1 + tid] = acc[r];
        float ss = wr_sum(acc[r] * av);
        float dd = wr_sum(acc[r] * dv);
        if (ln == 0) { s1[(n0 + r) * HEADS + h] = ss; d1[(n0 + r) * HEADS + h] = dd; }
    }
}

// ---------------- GAT aggregation layer 1 (concat) + LN(256) + ELU ----------------
// 8-deep wave-split gather (one unrolled trip covers most of a wave's ~11 neighbors
// at ~500cy LLC latency) + single-pass LN stats (E[x^2]-mu^2, saves 2 syncs/round).
__global__ __launch_bounds__(256) void k_agg1(const float* __restrict__ h1, const float* __restrict__ s1,
                                              const float* __restrict__ d1, const int* __restrict__ cnt,
                                              const int* __restrict__ idx, const float* __restrict__ g,
                                              const float* __restrict__ b, float* __restrict__ xo) {
    int i = blockIdx.x, tid = threadIdx.x;
    int wv = tid >> 6, lane = tid & 63;
    __shared__ int nbrs[MAXN];
    __shared__ float wts[HEADS][MAXN + 1];
    __shared__ float lsum[HEADS];
    __shared__ float sacc[4][F1];
    __shared__ float red[HEADS], red2[HEADS];
    int c = cnt[i];
    if (tid < c) nbrs[tid] = idx[i * MAXN + tid];
    __syncthreads();
    if (tid < c) {
        float4 dd = ((const float4*)d1)[nbrs[tid]];
        float4 ss = ((const float4*)s1)[i];
        float e0 = ss.x + dd.x, e1 = ss.y + dd.y, e2 = ss.z + dd.z, e3 = ss.w + dd.w;
        wts[0][tid] = e0 > 0.f ? e0 : 0.2f * e0;
        wts[1][tid] = e1 > 0.f ? e1 : 0.2f * e1;
        wts[2][tid] = e2 > 0.f ? e2 : 0.2f * e2;
        wts[3][tid] = e3 > 0.f ? e3 : 0.2f * e3;
    }
    __syncthreads();
    {   // per-head softmax normalize: wave wv owns head wv
        float m = -INFINITY;
        for (int jj = lane; jj < c; jj += 64) m = fmaxf(m, wts[wv][jj]);
        m = wr_max(m);
        float l = 0.f;
        for (int jj = lane; jj < c; jj += 64) { float t = expf(wts[wv][jj] - m); wts[wv][jj] = t; l += t; }
        l = wr_sum(l);
        if (lane == 0) lsum[wv] = l;
    }
    __syncthreads();
    int hq = lane >> 4;
    const float4* hv = (const float4*)h1;
    float4 acc = {0.f, 0.f, 0.f, 0.f};
    int jj = wv;
    for (; jj + 28 < c; jj += 32) {   // 8 loads in flight
        int n[8]; float w[8]; float4 v[8];
#pragma unroll
        for (int u = 0; u < 8; ++u) { n[u] = nbrs[jj + 4 * u]; w[u] = wts[hq][jj + 4 * u]; }
#pragma unroll
        for (int u = 0; u < 8; ++u) v[u] = hv[(size_t)n[u] * 64 + lane];
#pragma unroll
        for (int u = 0; u < 8; ++u) {
            acc.x = fmaf(w[u], v[u].x, acc.x); acc.y = fmaf(w[u], v[u].y, acc.y);
            acc.z = fmaf(w[u], v[u].z, acc.z); acc.w = fmaf(w[u], v[u].w, acc.w);
        }
    }
    for (; jj + 12 < c; jj += 16) {   // 4 loads in flight
        int n[4]; float w[4]; float4 v[4];
#pragma unroll
        for (int u = 0; u < 4; ++u) { n[u] = nbrs[jj + 4 * u]; w[u] = wts[hq][jj + 4 * u]; }
#pragma unroll
        for (int u = 0; u < 4; ++u) v[u] = hv[(size_t)n[u] * 64 + lane];
#pragma unroll
        for (int u = 0; u < 4; ++u) {
            acc.x = fmaf(w[u], v[u].x, acc.x); acc.y = fmaf(w[u], v[u].y, acc.y);
            acc.z = fmaf(w[u], v[u].z, acc.z); acc.w = fmaf(w[u], v[u].w, acc.w);
        }
    }
    for (; jj < c; jj += 4) {
        int na = nbrs[jj];
        float wa = wts[hq][jj];
        float4 va = hv[(size_t)na * 64 + lane];
        acc.x = fmaf(wa, va.x, acc.x); acc.y = fmaf(wa, va.y, acc.y);
        acc.z = fmaf(wa, va.z, acc.z); acc.w = fmaf(wa, va.w, acc.w);
    }
    ((float4*)&sacc[wv][0])[lane] = acc;
    __syncthreads();
    float tot = (sacc[0][tid] + sacc[1][tid] + sacc[2][tid] + sacc[3][tid]) / lsum[wv];
    float s = wr_sum(tot);
    float q = wr_sum(tot * tot);
    if (lane == 0) { red[wv] = s; red2[wv] = q; }
    __syncthreads();
    float mu = (red[0] + red[1] + red[2] + red[3]) * (1.f / F1);
    float ex2 = (red2[0] + red2[1] + red2[2] + red2[3]) * (1.f / F1);
    float var = ex2 - mu * mu;
    float y = (tot - mu) * rsqrtf(var + 1e-5f) * g[tid] + b[tid];
    xo[(size_t)i * F1 + tid] = y > 0.f ? y : expm1f(y);
}

// ---------------- GEMM2 [N,256]@[256,256] + fused attention dots (float4 LDS) ----------------
__global__ __launch_bounds__(256) void k_gemm2(const float* __restrict__ x1, const float* __restrict__ W2,
                                               const float* __restrict__ asrc, const float* __restrict__ adst,
                                               float* __restrict__ h2, float* __restrict__ s2, float* __restrict__ d2) {
    int n0 = blockIdx.x * RPB, tid = threadIdx.x;
    __shared__ float4 xs4[RPB][F1 / 4];
    {
        int r = tid >> 5, kk = tid & 31;
        const float4* x1v = (const float4*)x1;
        xs4[r][kk]      = x1v[(size_t)(n0 + r) * 64 + kk];
        xs4[r][kk + 32] = x1v[(size_t)(n0 + r) * 64 + kk + 32];
    }
    __syncthreads();
    float acc[RPB];
#pragma unroll
    for (int r = 0; r < RPB; ++r) acc[r] = 0.f;
#pragma unroll 4
    for (int kk = 0; kk < F1 / 4; ++kk) {
        float w0 = W2[(4 * kk + 0) * F1 + tid];
        float w1 = W2[(4 * kk + 1) * F1 + tid];
        float w2 = W2[(4 * kk + 2) * F1 + tid];
        float w3 = W2[(4 * kk + 3) * F1 + tid];
#pragma unroll
        for (int r = 0; r < RPB; ++r) {
            float4 x = xs4[r][kk];
            acc[r] = fmaf(x.x, w0, fmaf(x.y, w1, fmaf(x.z, w2, fmaf(x.w, w3, acc[r]))));
        }
    }
    int h = tid >> 6, lane = tid & 63;
    float av = asrc[tid], dv = adst[tid];
#pragma unroll
    for (int r = 0; r < RPB; ++r) {
        h2[(size_t)(n0 + r) * F1 + tid] = acc[r];
        float ss = wr_sum(acc[r] * av);
        float dd = wr_sum(acc[r] * dv);
        if (lane == 0) { s2[(n0 + r) * HEADS + h] = ss; d2[(n0 + r) * HEADS + h] = dd; }
    }
}

// ---------------- GAT aggregation layer 2 (mean heads) + LN(64) + ELU ----------------
__global__ __launch_bounds__(256) void k_agg2(const float* __restrict__ h2, const float* __restrict__ s2,
                                              const float* __restrict__ d2, const int* __restrict__ cnt,
                                              const int* __restrict__ idx, const float* __restrict__ g,
                                              const float* __restrict__ b, float* __restrict__ xo) {
    int i = blockIdx.x, tid = threadIdx.x;
    int wv = tid >> 6, lane = tid & 63;
    __shared__ int nbrs[MAXN];
    __shared__ float wts[HEADS][MAXN + 1];
    __shared__ float lsum[HEADS];
    __shared__ float sacc[4][F1];
    int c = cnt[i];
    if (tid < c) nbrs[tid] = idx[i * MAXN + tid];
    __syncthreads();
    if (tid < c) {
        float4 dd = ((const float4*)d2)[nbrs[tid]];
        float4 ss = ((const float4*)s2)[i];
        float e0 = ss.x + dd.x, e1 = ss.y + dd.y, e2 = ss.z + dd.z, e3 = ss.w + dd.w;
        wts[0][tid] = e0 > 0.f ? e0 : 0.2f * e0;
        wts[1][tid] = e1 > 0.f ? e1 : 0.2f * e1;
        wts[2][tid] = e2 > 0.f ? e2 : 0.2f * e2;
        wts[3][tid] = e3 > 0.f ? e3 : 0.2f * e3;
    }
    __syncthreads();
    {
        float m = -INFINITY;
        for (int jj = lane; jj < c; jj += 64) m = fmaxf(m, wts[wv][jj]);
        m = wr_max(m);
        float l = 0.f;
        for (int jj = lane; jj < c; jj += 64) { float t = expf(wts[wv][jj] - m); wts[wv][jj] = t; l += t; }
        l = wr_sum(l);
        if (lane == 0) lsum[wv] = l;
    }
    __syncthreads();
    int hq = lane >> 4;
    const float4* hvv = (const float4*)h2;
    float4 acc = {0.f, 0.f, 0.f, 0.f};
    int jj = wv;
    for (; jj + 28 < c; jj += 32) {   // 8 loads in flight
        int n[8]; float w[8]; float4 v[8];
#pragma unroll
        for (int u = 0; u < 8; ++u) { n[u] = nbrs[jj + 4 * u]; w[u] = wts[hq][jj + 4 * u]; }
#pragma unroll
        for (int u = 0; u < 8; ++u) v[u] = hvv[(size_t)n[u] * 64 + lane];
#pragma unroll
        for (int u = 0; u < 8; ++u) {
            acc.x = fmaf(w[u], v[u].x, acc.x); acc.y = fmaf(w[u], v[u].y, acc.y);
            acc.z = fmaf(w[u], v[u].z, acc.z); acc.w = fmaf(w[u], v[u].w, acc.w);
        }
    }
    for (; jj + 12 < c; jj += 16) {
        int n[4]; float w[4]; float4 v[4];
#pragma unroll
        for (int u = 0; u < 4; ++u) { n[u] = nbrs[jj + 4 * u]; w[u] = wts[hq][jj + 4 * u]; }
#pragma unroll
        for (int u = 0; u < 4; ++u) v[u] = hvv[(size_t)n[u] * 64 + lane];
#pragma unroll
        for (int u = 0; u < 4; ++u) {
            acc.x = fmaf(w[u], v[u].x, acc.x); acc.y = fmaf(w[u], v[u].y, acc.y);
            acc.z = fmaf(w[u], v[u].z, acc.z); acc.w = fmaf(w[u], v[u].w, acc.w);
        }
    }
    for (; jj < c; jj += 4) {
        int na = nbrs[jj];
        float wa = wts[hq][jj];
        float4 va = hvv[(size_t)na * 64 + lane];
        acc.x = fmaf(wa, va.x, acc.x); acc.y = fmaf(wa, va.y, acc.y);
        acc.z = fmaf(wa, va.z, acc.z); acc.w = fmaf(wa, va.w, acc.w);
    }
    ((float4*)&sacc[wv][0])[lane] = acc;
    __syncthreads();
    if (wv == 0) {
        float t0 = 0.f, t1 = 0.f, t2 = 0.f, t3 = 0.f;
#pragma unroll
        for (int w = 0; w < 4; ++w) {
            t0 += sacc[w][lane];
            t1 += sacc[w][lane + 64];
            t2 += sacc[w][lane + 128];
            t3 += sacc[w][lane + 192];
        }
        float mv = (t0 / lsum[0] + t1 / lsum[1] + t2 / lsum[2] + t3 / lsum[3]) * 0.25f;
        float mu = wr_sum(mv) * (1.f / HID);
        float q  = wr_sum(mv * mv) * (1.f / HID);
        float var = q - mu * mu;
        float y = (mv - mu) * rsqrtf(var + 1e-5f) * g[lane] + b[lane];
        xo[i * HID + lane] = y > 0.f ? y : expm1f(y);
    }
}

// ---------------- fused clause pooling + scorer ----------------
__global__ __launch_bounds__(256) void k_poolscore(const float* __restrict__ pm, const float* __restrict__ x2,
                                                   const float* __restrict__ Ws, const float* __restrict__ bs,
                                                   const float* __restrict__ Wo, const float* __restrict__ bo,
                                                   float* __restrict__ out) {
    int c = blockIdx.x, tid = threadIdx.x;
    int w = tid >> 6, lane = tid & 63;
    __shared__ float sacc[4][HID];
    __shared__ float ce_s[HID];
    float acc = 0.f;
    const float4* pmv = (const float4*)(pm + (size_t)c * N);
#pragma unroll
    for (int it = 0; it < 4; ++it) {
        int vi = w * 256 + it * 64 + lane;   // float4 index into the pm row
        float4 p4 = pmv[vi];
        float pc[4] = {p4.x, p4.y, p4.z, p4.w};
#pragma unroll
        for (int comp = 0; comp < 4; ++comp) {
            unsigned long long msk = __ballot(pc[comp] != 0.f);
            while (msk) {
                int bpos = __ffsll(msk) - 1;
                msk &= msk - 1;
                float pj = __shfl(pc[comp], bpos);
                int j = (w * 256 + it * 64 + bpos) * 4 + comp;
                acc += pj * x2[(size_t)j * HID + lane];
            }
        }
    }
    sacc[w][lane] = acc;
    __syncthreads();
    if (w == 0) ce_s[lane] = sacc[0][lane] + sacc[1][lane] + sacc[2][lane] + sacc[3][lane];
    __syncthreads();
    if (w == 0) {
        float hd = bs[lane];
#pragma unroll 8
        for (int k = 0; k < HID; ++k) hd = fmaf(ce_s[k], Ws[k * HID + lane], hd);
        hd = fmaxf(hd, 0.f);
        float v = wr_sum(hd * Wo[lane]);
        if (lane == 0) out[c] = v + bo[0];
    }
}

extern "C" void kernel_launch(void* const* d_in, const int* in_sizes, int n_in,
                              void* d_out, int out_size, void* d_ws, size_t ws_size,
                              hipStream_t stream) {
    const float* nf  = (const float*)d_in[0];
    const float* adj = (const float*)d_in[1];
    const float* pm  = (const float*)d_in[2];
    const float* W1  = (const float*)d_in[3];
    const float* as1 = (const float*)d_in[4];
    const float* ad1 = (const float*)d_in[5];
    const float* g1  = (const float*)d_in[6];
    const float* b1  = (const float*)d_in[7];
    const float* W2  = (const float*)d_in[8];
    const float* as2 = (const float*)d_in[9];
    const float* ad2 = (const float*)d_in[10];
    const float* g2  = (const float*)d_in[11];
    const float* b2  = (const float*)d_in[12];
    const float* Ws  = (const float*)d_in[13];
    const float* bs  = (const float*)d_in[14];
    const float* Wo  = (const float*)d_in[15];
    const float* bo  = (const float*)d_in[16];
    float* out = (float*)d_out;

    float* p = (float*)d_ws;
    float* h1  = p; p += (size_t)N * F1;
    float* s1  = p; p += (size_t)N * HEADS;
    float* d1  = p; p += (size_t)N * HEADS;
    float* x1  = p; p += (size_t)N * F1;
    float* h2  = p; p += (size_t)N * F1;
    float* s2  = p; p += (size_t)N * HEADS;
    float* d2  = p; p += (size_t)N * HEADS;
    float* x2  = p; p += (size_t)N * HID;
    int* cnt = (int*)p;
    int* idx = cnt + N;

    // 1536 blocks: 1024 build (4 rows each) interleaved 2:1 with 512 gemm1 blocks
    k_phase1<<<(N / 4) + (N / RPB), 256, 0, stream>>>(adj, cnt, idx, nf, W1, as1, ad1, h1, s1, d1);
    k_agg1<<<N, 256, 0, stream>>>(h1, s1, d1, cnt, idx, g1, b1, x1);
    k_gemm2<<<N / RPB, 256, 0, stream>>>(x1, W2, as2, ad2, h2, s2, d2);
    k_agg2<<<N, 256, 0, stream>>>(h2, s2, d2, cnt, idx, g2, b2, x2);
    k_poolscore<<<C, 256, 0, stream>>>(pm, x2, Ws, bs, Wo, bo, out);
}

// Round 2
// 197.841 us; speedup vs baseline: 1.0633x; 1.0633x over previous
//
#include <hip/hip_runtime.h>
#include <math.h>

#define N 4096
#define C 512
#define EMB 38
#define HEADS 4
#define HID 64
#define F1 256       // HEADS*HID
#define MAXN 128     // max neighbors per row (p=0.01 -> mean 41, >13 sigma headroom)
#define RPB 8        // rows per block in gemms

__device__ __forceinline__ float wr_sum(float v) {
#pragma unroll
    for (int o = 32; o > 0; o >>= 1) v += __shfl_xor(v, o);
    return v;
}
__device__ __forceinline__ float wr_max(float v) {
#pragma unroll
    for (int o = 32; o > 0; o >>= 1) v = fmaxf(v, __shfl_xor(v, o));
    return v;
}

// ---------------- PHASE 1 (fused): CSR build  ||  embed+GEMM1+attention dots ----------------
// build and gemm1 touch disjoint data (adj vs nf/W1) -> block-specialized fusion.
// Interleave 2 build blocks : 1 gemm1 block so HBM streaming (build) overlaps FMA (gemm1).
// R1 A/B note: this is the ONLY change vs the 196.6us R0 baseline; agg/gemm2 reverted
// to R0 exactly (R1's +14us suspected from their VGPR growth, not from this fusion).
__global__ __launch_bounds__(256) void k_phase1(const float* __restrict__ adj,
                                                int* __restrict__ cnt, int* __restrict__ idx,
                                                const float* __restrict__ nf, const float* __restrict__ W1,
                                                const float* __restrict__ asrc, const float* __restrict__ adst,
                                                float* __restrict__ h1, float* __restrict__ s1,
                                                float* __restrict__ d1) {
    int g = blockIdx.x / 3, r3 = blockIdx.x % 3;
    int tid = threadIdx.x;
    int wv = tid >> 6, lane = tid & 63;
    __shared__ int stage[4][MAXN];
    __shared__ float fs[RPB][8];
    __shared__ float xs[RPB][40];          // EMB=38 padded to 40, tail zeroed

    if (r3 != 2) {
        // ---- build path: block handles 4 adjacency rows, wave per row ----
        // full-row register load (16 float4 in flight), ballot compaction, LDS stage,
        // coalesced global write. (R8 lesson: depth-1 prefetch stuck at 2.2 TB/s.)
        int i = (2 * g + r3) * 4 + wv;
        const float4* row = (const float4*)(adj + (size_t)i * N);
        float4 v[16];
#pragma unroll
        for (int it = 0; it < 16; ++it) v[it] = row[it * 64 + lane];
        unsigned long long below = (1ull << lane) - 1;
        int base = 0;
#pragma unroll
        for (int it = 0; it < 16; ++it) {
            int col0 = 4 * (it * 64 + lane);
            float vals[4] = {v[it].x, v[it].y, v[it].z, v[it].w};
#pragma unroll
            for (int comp = 0; comp < 4; ++comp) {
                unsigned long long m = __ballot(vals[comp] > 0.f);
                if (vals[comp] > 0.f) {
                    int p = base + __popcll(m & below);
                    if (p < MAXN) stage[wv][p] = col0 + comp;
                }
                base += __popcll(m);
            }
        }
        int c = min(base, MAXN);
        __syncthreads();
        if (lane < c)      idx[i * MAXN + lane]      = stage[wv][lane];
        if (lane + 64 < c) idx[i * MAXN + lane + 64] = stage[wv][lane + 64];
        if (lane == 0) cnt[i] = c;
        return;
    }

    // ---- gemm1 path: 8 nodes/block, embed 38 features then 38->256 ----
    int n0 = g * RPB;
    if (tid < RPB * 8) fs[tid >> 3][tid & 7] = nf[(size_t)n0 * 8 + tid];
    if (tid < RPB * 2) xs[tid >> 1][38 + (tid & 1)] = 0.f;
    __syncthreads();
    {
        int r = tid & 7;
        int t = tid >> 3;               // 0..31
        const float* f = fs[r];
        for (int pass = 0; pass < 2; ++pass, t += 32) {
            if (t >= EMB) break;
            float val;
            if (t < 6) { int nt = min(max((int)f[0], 0), 5); val = (t == nt) ? 1.f : 0.f; }
            else if (t == 6) val = log1pf(f[1]);
            else if (t < 31) {
                int q = (t - 7) & 7, s = (t - 7) >> 3, m = q >> 1;
                float base = (s == 0) ? f[2] : (s == 1) ? f[3] : f[4] * 100.f;
                float div = expf((2.f * m) * (-logf(10000.f) / 8.f));
                float sc = base * div;
                val = (q & 1) ? cosf(sc) : sinf(sc);
            }
            else if (t < 36) { int role = min(max((int)f[5], 0), 4); val = (t - 31 == role) ? 1.f : 0.f; }
            else val = (t == 36) ? f[6] : f[7];
            xs[r][t] = val;
        }
    }
    __syncthreads();
    float acc[RPB];
#pragma unroll
    for (int r = 0; r < RPB; ++r) acc[r] = 0.f;
#pragma unroll
    for (int kk = 0; kk < 9; ++kk) {      // k = 0..35 via float4 LDS broadcast
        float w0 = W1[(4 * kk + 0) * F1 + tid];
        float w1 = W1[(4 * kk + 1) * F1 + tid];
        float w2 = W1[(4 * kk + 2) * F1 + tid];
        float w3 = W1[(4 * kk + 3) * F1 + tid];
#pragma unroll
        for (int r = 0; r < RPB; ++r) {
            float4 x = *(const float4*)&xs[r][4 * kk];
            acc[r] = fmaf(x.x, w0, fmaf(x.y, w1, fmaf(x.z, w2, fmaf(x.w, w3, acc[r]))));
        }
    }
#pragma unroll
    for (int k = 36; k < EMB; ++k) {      // tail
        float wvv = W1[k * F1 + tid];
#pragma unroll
        for (int r = 0; r < RPB; ++r) acc[r] = fmaf(xs[r][k], wvv, acc[r]);
    }
    int h = tid >> 6, ln = tid & 63;
    float av = asrc[tid], dv = adst[tid];
#pragma unroll
    for (int r = 0; r < RPB; ++r) {
        h1[(size_t)(n0 + r) * F1 + tid] = acc[r];
        float ss = wr_sum(acc[r] * av);
        float dd = wr_sum(acc[r] * dv);
        if (ln == 0) { s1[(n0 + r) * HEADS + h] = ss; d1[(n0 + r) * HEADS + h] = dd; }
    }
}

// ---------------- GAT aggregation layer 1 (concat) + LN(256) + ELU: 4-deep wave-split gather ----------------
__global__ __launch_bounds__(256) void k_agg1(const float* __restrict__ h1, const float* __restrict__ s1,
                                              const float* __restrict__ d1, const int* __restrict__ cnt,
                                              const int* __restrict__ idx, const float* __restrict__ g,
                                              const float* __restrict__ b, float* __restrict__ xo) {
    int i = blockIdx.x, tid = threadIdx.x;
    int wv = tid >> 6, lane = tid & 63;
    __shared__ int nbrs[MAXN];
    __shared__ float wts[HEADS][MAXN + 1];
    __shared__ float lsum[HEADS];
    __shared__ float sacc[4][F1];
    __shared__ float red[HEADS];
    int c = cnt[i];
    if (tid < c) nbrs[tid] = idx[i * MAXN + tid];
    __syncthreads();
    if (tid < c) {
        float4 dd = ((const float4*)d1)[nbrs[tid]];
        float4 ss = ((const float4*)s1)[i];
        float e0 = ss.x + dd.x, e1 = ss.y + dd.y, e2 = ss.z + dd.z, e3 = ss.w + dd.w;
        wts[0][tid] = e0 > 0.f ? e0 : 0.2f * e0;
        wts[1][tid] = e1 > 0.f ? e1 : 0.2f * e1;
        wts[2][tid] = e2 > 0.f ? e2 : 0.2f * e2;
        wts[3][tid] = e3 > 0.f ? e3 : 0.2f * e3;
    }
    __syncthreads();
    {   // per-head softmax normalize: wave wv owns head wv
        float m = -INFINITY;
        for (int jj = lane; jj < c; jj += 64) m = fmaxf(m, wts[wv][jj]);
        m = wr_max(m);
        float l = 0.f;
        for (int jj = lane; jj < c; jj += 64) { float t = expf(wts[wv][jj] - m); wts[wv][jj] = t; l += t; }
        l = wr_sum(l);
        if (lane == 0) lsum[wv] = l;
    }
    __syncthreads();
    int hq = lane >> 4;
    const float4* hv = (const float4*)h1;
    float4 acc = {0.f, 0.f, 0.f, 0.f};
    int jj = wv;
    for (; jj + 12 < c; jj += 16) {   // 4 loads in flight
        int na = nbrs[jj], nb = nbrs[jj + 4], nc = nbrs[jj + 8], nd = nbrs[jj + 12];
        float wa = wts[hq][jj], wb = wts[hq][jj + 4], wc = wts[hq][jj + 8], wd = wts[hq][jj + 12];
        float4 va = hv[(size_t)na * 64 + lane];
        float4 vb = hv[(size_t)nb * 64 + lane];
        float4 vc = hv[(size_t)nc * 64 + lane];
        float4 vd = hv[(size_t)nd * 64 + lane];
        acc.x = fmaf(wa, va.x, acc.x); acc.y = fmaf(wa, va.y, acc.y);
        acc.z = fmaf(wa, va.z, acc.z); acc.w = fmaf(wa, va.w, acc.w);
        acc.x = fmaf(wb, vb.x, acc.x); acc.y = fmaf(wb, vb.y, acc.y);
        acc.z = fmaf(wb, vb.z, acc.z); acc.w = fmaf(wb, vb.w, acc.w);
        acc.x = fmaf(wc, vc.x, acc.x); acc.y = fmaf(wc, vc.y, acc.y);
        acc.z = fmaf(wc, vc.z, acc.z); acc.w = fmaf(wc, vc.w, acc.w);
        acc.x = fmaf(wd, vd.x, acc.x); acc.y = fmaf(wd, vd.y, acc.y);
        acc.z = fmaf(wd, vd.z, acc.z); acc.w = fmaf(wd, vd.w, acc.w);
    }
    for (; jj < c; jj += 4) {
        int na = nbrs[jj];
        float wa = wts[hq][jj];
        float4 va = hv[(size_t)na * 64 + lane];
        acc.x = fmaf(wa, va.x, acc.x); acc.y = fmaf(wa, va.y, acc.y);
        acc.z = fmaf(wa, va.z, acc.z); acc.w = fmaf(wa, va.w, acc.w);
    }
    ((float4*)&sacc[wv][0])[lane] = acc;
    __syncthreads();
    float tot = (sacc[0][tid] + sacc[1][tid] + sacc[2][tid] + sacc[3][tid]) / lsum[wv];
    float s = wr_sum(tot);
    if (lane == 0) red[wv] = s;
    __syncthreads();
    float mu = (red[0] + red[1] + red[2] + red[3]) * (1.f / F1);
    float dvv = tot - mu;
    float s2 = wr_sum(dvv * dvv);
    __syncthreads();
    if (lane == 0) red[wv] = s2;
    __syncthreads();
    float var = (red[0] + red[1] + red[2] + red[3]) * (1.f / F1);
    float y = dvv * rsqrtf(var + 1e-5f) * g[tid] + b[tid];
    xo[(size_t)i * F1 + tid] = y > 0.f ? y : expm1f(y);
}

// ---------------- GEMM2 [N,256]@[256,256] + fused attention dots (float4 LDS) ----------------
__global__ __launch_bounds__(256) void k_gemm2(const float* __restrict__ x1, const float* __restrict__ W2,
                                               const float* __restrict__ asrc, const float* __restrict__ adst,
                                               float* __restrict__ h2, float* __restrict__ s2, float* __restrict__ d2) {
    int n0 = blockIdx.x * RPB, tid = threadIdx.x;
    __shared__ float4 xs4[RPB][F1 / 4];
    {
        int r = tid >> 5, kk = tid & 31;
        const float4* x1v = (const float4*)x1;
        xs4[r][kk]      = x1v[(size_t)(n0 + r) * 64 + kk];
        xs4[r][kk + 32] = x1v[(size_t)(n0 + r) * 64 + kk + 32];
    }
    __syncthreads();
    float acc[RPB];
#pragma unroll
    for (int r = 0; r < RPB; ++r) acc[r] = 0.f;
    for (int kk = 0; kk < F1 / 4; ++kk) {
        float w0 = W2[(4 * kk + 0) * F1 + tid];
        float w1 = W2[(4 * kk + 1) * F1 + tid];
        float w2 = W2[(4 * kk + 2) * F1 + tid];
        float w3 = W2[(4 * kk + 3) * F1 + tid];
#pragma unroll
        for (int r = 0; r < RPB; ++r) {
            float4 x = xs4[r][kk];
            acc[r] = fmaf(x.x, w0, fmaf(x.y, w1, fmaf(x.z, w2, fmaf(x.w, w3, acc[r]))));
        }
    }
    int h = tid >> 6, lane = tid & 63;
    float av = asrc[tid], dv = adst[tid];
#pragma unroll
    for (int r = 0; r < RPB; ++r) {
        h2[(size_t)(n0 + r) * F1 + tid] = acc[r];
        float ss = wr_sum(acc[r] * av);
        float dd = wr_sum(acc[r] * dv);
        if (lane == 0) { s2[(n0 + r) * HEADS + h] = ss; d2[(n0 + r) * HEADS + h] = dd; }
    }
}

// ---------------- GAT aggregation layer 2 (mean heads) + LN(64) + ELU: 4-deep wave-split gather ----------------
__global__ __launch_bounds__(256) void k_agg2(const float* __restrict__ h2, const float* __restrict__ s2,
                                              const float* __restrict__ d2, const int* __restrict__ cnt,
                                              const int* __restrict__ idx, const float* __restrict__ g,
                                              const float* __restrict__ b, float* __restrict__ xo) {
    int i = blockIdx.x, tid = threadIdx.x;
    int wv = tid >> 6, lane = tid & 63;
    __shared__ int nbrs[MAXN];
    __shared__ float wts[HEADS][MAXN + 1];
    __shared__ float lsum[HEADS];
    __shared__ float sacc[4][F1];
    int c = cnt[i];
    if (tid < c) nbrs[tid] = idx[i * MAXN + tid];
    __syncthreads();
    if (tid < c) {
        float4 dd = ((const float4*)d2)[nbrs[tid]];
        float4 ss = ((const float4*)s2)[i];
        float e0 = ss.x + dd.x, e1 = ss.y + dd.y, e2 = ss.z + dd.z, e3 = ss.w + dd.w;
        wts[0][tid] = e0 > 0.f ? e0 : 0.2f * e0;
        wts[1][tid] = e1 > 0.f ? e1 : 0.2f * e1;
        wts[2][tid] = e2 > 0.f ? e2 : 0.2f * e2;
        wts[3][tid] = e3 > 0.f ? e3 : 0.2f * e3;
    }
    __syncthreads();
    {
        float m = -INFINITY;
        for (int jj = lane; jj < c; jj += 64) m = fmaxf(m, wts[wv][jj]);
        m = wr_max(m);
        float l = 0.f;
        for (int jj = lane; jj < c; jj += 64) { float t = expf(wts[wv][jj] - m); wts[wv][jj] = t; l += t; }
        l = wr_sum(l);
        if (lane == 0) lsum[wv] = l;
    }
    __syncthreads();
    int hq = lane >> 4;
    const float4* hvv = (const float4*)h2;
    float4 acc = {0.f, 0.f, 0.f, 0.f};
    int jj = wv;
    for (; jj + 12 < c; jj += 16) {
        int na = nbrs[jj], nb = nbrs[jj + 4], nc = nbrs[jj + 8], nd = nbrs[jj + 12];
        float wa = wts[hq][jj], wb = wts[hq][jj + 4], wc = wts[hq][jj + 8], wd = wts[hq][jj + 12];
        float4 va = hvv[(size_t)na * 64 + lane];
        float4 vb = hvv[(size_t)nb * 64 + lane];
        float4 vc = hvv[(size_t)nc * 64 + lane];
        float4 vd = hvv[(size_t)nd * 64 + lane];
        acc.x = fmaf(wa, va.x, acc.x); acc.y = fmaf(wa, va.y, acc.y);
        acc.z = fmaf(wa, va.z, acc.z); acc.w = fmaf(wa, va.w, acc.w);
        acc.x = fmaf(wb, vb.x, acc.x); acc.y = fmaf(wb, vb.y, acc.y);
        acc.z = fmaf(wb, vb.z, acc.z); acc.w = fmaf(wb, vb.w, acc.w);
        acc.x = fmaf(wc, vc.x, acc.x); acc.y = fmaf(wc, vc.y, acc.y);
        acc.z = fmaf(wc, vc.z, acc.z); acc.w = fmaf(wc, vc.w, acc.w);
        acc.x = fmaf(wd, vd.x, acc.x); acc.y = fmaf(wd, vd.y, acc.y);
        acc.z = fmaf(wd, vd.z, acc.z); acc.w = fmaf(wd, vd.w, acc.w);
    }
    for (; jj < c; jj += 4) {
        int na = nbrs[jj];
        float wa = wts[hq][jj];
        float4 va = hvv[(size_t)na * 64 + lane];
        acc.x = fmaf(wa, va.x, acc.x); acc.y = fmaf(wa, va.y, acc.y);
        acc.z = fmaf(wa, va.z, acc.z); acc.w = fmaf(wa, va.w, acc.w);
    }
    ((float4*)&sacc[wv][0])[lane] = acc;
    __syncthreads();
    if (wv == 0) {
        float t0 = 0.f, t1 = 0.f, t2 = 0.f, t3 = 0.f;
#pragma unroll
        for (int w = 0; w < 4; ++w) {
            t0 += sacc[w][lane];
            t1 += sacc[w][lane + 64];
            t2 += sacc[w][lane + 128];
            t3 += sacc[w][lane + 192];
        }
        float mv = (t0 / lsum[0] + t1 / lsum[1] + t2 / lsum[2] + t3 / lsum[3]) * 0.25f;
        float mu = wr_sum(mv) * (1.f / HID);
        float dvv = mv - mu;
        float var = wr_sum(dvv * dvv) * (1.f / HID);
        float y = dvv * rsqrtf(var + 1e-5f) * g[lane] + b[lane];
        xo[i * HID + lane] = y > 0.f ? y : expm1f(y);
    }
}

// ---------------- fused clause pooling + scorer ----------------
__global__ __launch_bounds__(256) void k_poolscore(const float* __restrict__ pm, const float* __restrict__ x2,
                                                   const float* __restrict__ Ws, const float* __restrict__ bs,
                                                   const float* __restrict__ Wo, const float* __restrict__ bo,
                                                   float* __restrict__ out) {
    int c = blockIdx.x, tid = threadIdx.x;
    int w = tid >> 6, lane = tid & 63;
    __shared__ float sacc[4][HID];
    __shared__ float ce_s[HID];
    float acc = 0.f;
    const float4* pmv = (const float4*)(pm + (size_t)c * N);
#pragma unroll
    for (int it = 0; it < 4; ++it) {
        int vi = w * 256 + it * 64 + lane;   // float4 index into the pm row
        float4 p4 = pmv[vi];
        float pc[4] = {p4.x, p4.y, p4.z, p4.w};
#pragma unroll
        for (int comp = 0; comp < 4; ++comp) {
            unsigned long long msk = __ballot(pc[comp] != 0.f);
            while (msk) {
                int bpos = __ffsll(msk) - 1;
                msk &= msk - 1;
                float pj = __shfl(pc[comp], bpos);
                int j = (w * 256 + it * 64 + bpos) * 4 + comp;
                acc += pj * x2[(size_t)j * HID + lane];
            }
        }
    }
    sacc[w][lane] = acc;
    __syncthreads();
    if (w == 0) ce_s[lane] = sacc[0][lane] + sacc[1][lane] + sacc[2][lane] + sacc[3][lane];
    __syncthreads();
    if (w == 0) {
        float hd = bs[lane];
#pragma unroll 8
        for (int k = 0; k < HID; ++k) hd = fmaf(ce_s[k], Ws[k * HID + lane], hd);
        hd = fmaxf(hd, 0.f);
        float v = wr_sum(hd * Wo[lane]);
        if (lane == 0) out[c] = v + bo[0];
    }
}

extern "C" void kernel_launch(void* const* d_in, const int* in_sizes, int n_in,
                              void* d_out, int out_size, void* d_ws, size_t ws_size,
                              hipStream_t stream) {
    const float* nf  = (const float*)d_in[0];
    const float* adj = (const float*)d_in[1];
    const float* pm  = (const float*)d_in[2];
    const float* W1  = (const float*)d_in[3];
    const float* as1 = (const float*)d_in[4];
    const float* ad1 = (const float*)d_in[5];
    const float* g1  = (const float*)d_in[6];
    const float* b1  = (const float*)d_in[7];
    const float* W2  = (const float*)d_in[8];
    const float* as2 = (const float*)d_in[9];
    const float* ad2 = (const float*)d_in[10];
    const float* g2  = (const float*)d_in[11];
    const float* b2  = (const float*)d_in[12];
    const float* Ws  = (const float*)d_in[13];
    const float* bs  = (const float*)d_in[14];
    const float* Wo  = (const float*)d_in[15];
    const float* bo  = (const float*)d_in[16];
    float* out = (float*)d_out;

    float* p = (float*)d_ws;
    float* h1  = p; p += (size_t)N * F1;
    float* s1  = p; p += (size_t)N * HEADS;
    float* d1  = p; p += (size_t)N * HEADS;
    float* x1  = p; p += (size_t)N * F1;
    float* h2  = p; p += (size_t)N * F1;
    float* s2  = p; p += (size_t)N * HEADS;
    float* d2  = p; p += (size_t)N * HEADS;
    float* x2  = p; p += (size_t)N * HID;
    int* cnt = (int*)p;
    int* idx = cnt + N;

    // 1536 blocks: 1024 build (4 rows each) interleaved 2:1 with 512 gemm1 blocks
    k_phase1<<<(N / 4) + (N / RPB), 256, 0, stream>>>(adj, cnt, idx, nf, W1, as1, ad1, h1, s1, d1);
    k_agg1<<<N, 256, 0, stream>>>(h1, s1, d1, cnt, idx, g1, b1, x1);
    k_gemm2<<<N / RPB, 256, 0, stream>>>(x1, W2, as2, ad2, h2, s2, d2);
    k_agg2<<<N, 256, 0, stream>>>(h2, s2, d2, cnt, idx, g2, b2, x2);
    k_poolscore<<<C, 512 / 2, 0, stream>>>(pm, x2, Ws, bs, Wo, bo, out);
}

// Round 3
// 195.293 us; speedup vs baseline: 1.0772x; 1.0130x over previous
//
#include <hip/hip_runtime.h>
#include <math.h>

#define N 4096
#define C 512
#define EMB 38
#define HEADS 4
#define HID 64
#define F1 256       // HEADS*HID
#define MAXN 128     // max neighbors per row (p=0.01 -> mean 41, >13 sigma headroom)
#define RPB 8        // rows per block in gemms

__device__ __forceinline__ float wr_sum(float v) {
#pragma unroll
    for (int o = 32; o > 0; o >>= 1) v += __shfl_xor(v, o);
    return v;
}
__device__ __forceinline__ float wr_max(float v) {
#pragma unroll
    for (int o = 32; o > 0; o >>= 1) v = fmaxf(v, __shfl_xor(v, o));
    return v;
}

// ---------------- build CSR: BLOCK per row, 256 threads ----------------
// R2 counters showed the old wave-per-row build at 778 GB/s / 8% occupancy / 164 VGPR
// (fused): latency-bound. This version: scalar stride-64 loads (16 per thread, all in
// flight), ballot masks in SGPRs, ~40 VGPR, 16B LDS -> 8 waves/SIMD, HBM-bound.
// Column order within a row is ascending (wave-major, iter, lane) - matches reference.
__global__ __launch_bounds__(256) void k_build(const float* __restrict__ adj,
                                               int* __restrict__ cnt, int* __restrict__ idx) {
    int i = blockIdx.x, tid = threadIdx.x;
    int wv = tid >> 6, lane = tid & 63;
    __shared__ int wcnt[4];
    const float* row = adj + (size_t)i * N;
    float v[16];
#pragma unroll
    for (int k = 0; k < 16; ++k) v[k] = row[wv * 1024 + k * 64 + lane];  // all 16 issued
    unsigned long long m[16];
    int tot = 0;
#pragma unroll
    for (int k = 0; k < 16; ++k) { m[k] = __ballot(v[k] > 0.f); tot += __popcll(m[k]); }
    if (lane == 0) wcnt[wv] = tot;
    __syncthreads();
    int base = 0;
#pragma unroll
    for (int w = 0; w < 4; ++w) if (w < wv) base += wcnt[w];
    int total = wcnt[0] + wcnt[1] + wcnt[2] + wcnt[3];
    unsigned long long below = (1ull << lane) - 1;
    int off = base;
#pragma unroll
    for (int k = 0; k < 16; ++k) {
        if (v[k] > 0.f) {
            int p = off + __popcll(m[k] & below);
            if (p < MAXN) idx[i * MAXN + p] = wv * 1024 + k * 64 + lane;
        }
        off += __popcll(m[k]);
    }
    if (tid == 0) cnt[i] = min(total, MAXN);
}

// ---------------- fused embed + GEMM1 [8 nodes/block: 38->256] + attention dots (R0 exact) ----------------
__global__ __launch_bounds__(256) void k_gemm1(const float* __restrict__ nf, const float* __restrict__ W1,
                                               const float* __restrict__ asrc, const float* __restrict__ adst,
                                               float* __restrict__ h1, float* __restrict__ s1, float* __restrict__ d1) {
    int n0 = blockIdx.x * RPB, tid = threadIdx.x;
    __shared__ float fs[RPB][8];
    __shared__ float xs[RPB][40];          // EMB=38 padded to 40, tail zeroed
    if (tid < RPB * 8) fs[tid >> 3][tid & 7] = nf[(size_t)n0 * 8 + tid];
    if (tid < RPB * 2) xs[tid >> 1][38 + (tid & 1)] = 0.f;
    __syncthreads();
    {
        int r = tid & 7;
        int t = tid >> 3;               // 0..31
        const float* f = fs[r];
        for (int pass = 0; pass < 2; ++pass, t += 32) {
            if (t >= EMB) break;
            float val;
            if (t < 6) { int nt = min(max((int)f[0], 0), 5); val = (t == nt) ? 1.f : 0.f; }
            else if (t == 6) val = log1pf(f[1]);
            else if (t < 31) {
                int q = (t - 7) & 7, s = (t - 7) >> 3, m = q >> 1;
                float base = (s == 0) ? f[2] : (s == 1) ? f[3] : f[4] * 100.f;
                float div = expf((2.f * m) * (-logf(10000.f) / 8.f));
                float sc = base * div;
                val = (q & 1) ? cosf(sc) : sinf(sc);
            }
            else if (t < 36) { int role = min(max((int)f[5], 0), 4); val = (t - 31 == role) ? 1.f : 0.f; }
            else val = (t == 36) ? f[6] : f[7];
            xs[r][t] = val;
        }
    }
    __syncthreads();
    float acc[RPB];
#pragma unroll
    for (int r = 0; r < RPB; ++r) acc[r] = 0.f;
#pragma unroll
    for (int kk = 0; kk < 9; ++kk) {      // k = 0..35 via float4 LDS broadcast
        float w0 = W1[(4 * kk + 0) * F1 + tid];
        float w1 = W1[(4 * kk + 1) * F1 + tid];
        float w2 = W1[(4 * kk + 2) * F1 + tid];
        float w3 = W1[(4 * kk + 3) * F1 + tid];
#pragma unroll
        for (int r = 0; r < RPB; ++r) {
            float4 x = *(const float4*)&xs[r][4 * kk];
            acc[r] = fmaf(x.x, w0, fmaf(x.y, w1, fmaf(x.z, w2, fmaf(x.w, w3, acc[r]))));
        }
    }
#pragma unroll
    for (int k = 36; k < EMB; ++k) {      // tail
        float wvv = W1[k * F1 + tid];
#pragma unroll
        for (int r = 0; r < RPB; ++r) acc[r] = fmaf(xs[r][k], wvv, acc[r]);
    }
    int h = tid >> 6, lane = tid & 63;
    float av = asrc[tid], dv = adst[tid];
#pragma unroll
    for (int r = 0; r < RPB; ++r) {
        h1[(size_t)(n0 + r) * F1 + tid] = acc[r];
        float ss = wr_sum(acc[r] * av);
        float dd = wr_sum(acc[r] * dv);
        if (lane == 0) { s1[(n0 + r) * HEADS + h] = ss; d1[(n0 + r) * HEADS + h] = dd; }
    }
}

// ---------------- GAT aggregation layer 1 (concat) + LN(256) + ELU: 4-deep wave-split gather ----------------
__global__ __launch_bounds__(256) void k_agg1(const float* __restrict__ h1, const float* __restrict__ s1,
                                              const float* __restrict__ d1, const int* __restrict__ cnt,
                                              const int* __restrict__ idx, const float* __restrict__ g,
                                              const float* __restrict__ b, float* __restrict__ xo) {
    int i = blockIdx.x, tid = threadIdx.x;
    int wv = tid >> 6, lane = tid & 63;
    __shared__ int nbrs[MAXN];
    __shared__ float wts[HEADS][MAXN + 1];
    __shared__ float lsum[HEADS];
    __shared__ float sacc[4][F1];
    __shared__ float red[HEADS];
    int c = cnt[i];
    if (tid < c) nbrs[tid] = idx[i * MAXN + tid];
    __syncthreads();
    if (tid < c) {
        float4 dd = ((const float4*)d1)[nbrs[tid]];
        float4 ss = ((const float4*)s1)[i];
        float e0 = ss.x + dd.x, e1 = ss.y + dd.y, e2 = ss.z + dd.z, e3 = ss.w + dd.w;
        wts[0][tid] = e0 > 0.f ? e0 : 0.2f * e0;
        wts[1][tid] = e1 > 0.f ? e1 : 0.2f * e1;
        wts[2][tid] = e2 > 0.f ? e2 : 0.2f * e2;
        wts[3][tid] = e3 > 0.f ? e3 : 0.2f * e3;
    }
    __syncthreads();
    {   // per-head softmax normalize: wave wv owns head wv
        float m = -INFINITY;
        for (int jj = lane; jj < c; jj += 64) m = fmaxf(m, wts[wv][jj]);
        m = wr_max(m);
        float l = 0.f;
        for (int jj = lane; jj < c; jj += 64) { float t = expf(wts[wv][jj] - m); wts[wv][jj] = t; l += t; }
        l = wr_sum(l);
        if (lane == 0) lsum[wv] = l;
    }
    __syncthreads();
    int hq = lane >> 4;
    const float4* hv = (const float4*)h1;
    float4 acc = {0.f, 0.f, 0.f, 0.f};
    int jj = wv;
    for (; jj + 12 < c; jj += 16) {   // 4 loads in flight
        int na = nbrs[jj], nb = nbrs[jj + 4], nc = nbrs[jj + 8], nd = nbrs[jj + 12];
        float wa = wts[hq][jj], wb = wts[hq][jj + 4], wc = wts[hq][jj + 8], wd = wts[hq][jj + 12];
        float4 va = hv[(size_t)na * 64 + lane];
        float4 vb = hv[(size_t)nb * 64 + lane];
        float4 vc = hv[(size_t)nc * 64 + lane];
        float4 vd = hv[(size_t)nd * 64 + lane];
        acc.x = fmaf(wa, va.x, acc.x); acc.y = fmaf(wa, va.y, acc.y);
        acc.z = fmaf(wa, va.z, acc.z); acc.w = fmaf(wa, va.w, acc.w);
        acc.x = fmaf(wb, vb.x, acc.x); acc.y = fmaf(wb, vb.y, acc.y);
        acc.z = fmaf(wb, vb.z, acc.z); acc.w = fmaf(wb, vb.w, acc.w);
        acc.x = fmaf(wc, vc.x, acc.x); acc.y = fmaf(wc, vc.y, acc.y);
        acc.z = fmaf(wc, vc.z, acc.z); acc.w = fmaf(wc, vc.w, acc.w);
        acc.x = fmaf(wd, vd.x, acc.x); acc.y = fmaf(wd, vd.y, acc.y);
        acc.z = fmaf(wd, vd.z, acc.z); acc.w = fmaf(wd, vd.w, acc.w);
    }
    for (; jj < c; jj += 4) {
        int na = nbrs[jj];
        float wa = wts[hq][jj];
        float4 va = hv[(size_t)na * 64 + lane];
        acc.x = fmaf(wa, va.x, acc.x); acc.y = fmaf(wa, va.y, acc.y);
        acc.z = fmaf(wa, va.z, acc.z); acc.w = fmaf(wa, va.w, acc.w);
    }
    ((float4*)&sacc[wv][0])[lane] = acc;
    __syncthreads();
    float tot = (sacc[0][tid] + sacc[1][tid] + sacc[2][tid] + sacc[3][tid]) / lsum[wv];
    float s = wr_sum(tot);
    if (lane == 0) red[wv] = s;
    __syncthreads();
    float mu = (red[0] + red[1] + red[2] + red[3]) * (1.f / F1);
    float dvv = tot - mu;
    float s2 = wr_sum(dvv * dvv);
    __syncthreads();
    if (lane == 0) red[wv] = s2;
    __syncthreads();
    float var = (red[0] + red[1] + red[2] + red[3]) * (1.f / F1);
    float y = dvv * rsqrtf(var + 1e-5f) * g[tid] + b[tid];
    xo[(size_t)i * F1 + tid] = y > 0.f ? y : expm1f(y);
}

// ---------------- GEMM2 [N,256]@[256,256] + fused attention dots (float4 LDS) ----------------
__global__ __launch_bounds__(256) void k_gemm2(const float* __restrict__ x1, const float* __restrict__ W2,
                                               const float* __restrict__ asrc, const float* __restrict__ adst,
                                               float* __restrict__ h2, float* __restrict__ s2, float* __restrict__ d2) {
    int n0 = blockIdx.x * RPB, tid = threadIdx.x;
    __shared__ float4 xs4[RPB][F1 / 4];
    {
        int r = tid >> 5, kk = tid & 31;
        const float4* x1v = (const float4*)x1;
        xs4[r][kk]      = x1v[(size_t)(n0 + r) * 64 + kk];
        xs4[r][kk + 32] = x1v[(size_t)(n0 + r) * 64 + kk + 32];
    }
    __syncthreads();
    float acc[RPB];
#pragma unroll
    for (int r = 0; r < RPB; ++r) acc[r] = 0.f;
    for (int kk = 0; kk < F1 / 4; ++kk) {
        float w0 = W2[(4 * kk + 0) * F1 + tid];
        float w1 = W2[(4 * kk + 1) * F1 + tid];
        float w2 = W2[(4 * kk + 2) * F1 + tid];
        float w3 = W2[(4 * kk + 3) * F1 + tid];
#pragma unroll
        for (int r = 0; r < RPB; ++r) {
            float4 x = xs4[r][kk];
            acc[r] = fmaf(x.x, w0, fmaf(x.y, w1, fmaf(x.z, w2, fmaf(x.w, w3, acc[r]))));
        }
    }
    int h = tid >> 6, lane = tid & 63;
    float av = asrc[tid], dv = adst[tid];
#pragma unroll
    for (int r = 0; r < RPB; ++r) {
        h2[(size_t)(n0 + r) * F1 + tid] = acc[r];
        float ss = wr_sum(acc[r] * av);
        float dd = wr_sum(acc[r] * dv);
        if (lane == 0) { s2[(n0 + r) * HEADS + h] = ss; d2[(n0 + r) * HEADS + h] = dd; }
    }
}

// ---------------- GAT aggregation layer 2 (mean heads) + LN(64) + ELU: 4-deep wave-split gather ----------------
__global__ __launch_bounds__(256) void k_agg2(const float* __restrict__ h2, const float* __restrict__ s2,
                                              const float* __restrict__ d2, const int* __restrict__ cnt,
                                              const int* __restrict__ idx, const float* __restrict__ g,
                                              const float* __restrict__ b, float* __restrict__ xo) {
    int i = blockIdx.x, tid = threadIdx.x;
    int wv = tid >> 6, lane = tid & 63;
    __shared__ int nbrs[MAXN];
    __shared__ float wts[HEADS][MAXN + 1];
    __shared__ float lsum[HEADS];
    __shared__ float sacc[4][F1];
    int c = cnt[i];
    if (tid < c) nbrs[tid] = idx[i * MAXN + tid];
    __syncthreads();
    if (tid < c) {
        float4 dd = ((const float4*)d2)[nbrs[tid]];
        float4 ss = ((const float4*)s2)[i];
        float e0 = ss.x + dd.x, e1 = ss.y + dd.y, e2 = ss.z + dd.z, e3 = ss.w + dd.w;
        wts[0][tid] = e0 > 0.f ? e0 : 0.2f * e0;
        wts[1][tid] = e1 > 0.f ? e1 : 0.2f * e1;
        wts[2][tid] = e2 > 0.f ? e2 : 0.2f * e2;
        wts[3][tid] = e3 > 0.f ? e3 : 0.2f * e3;
    }
    __syncthreads();
    {
        float m = -INFINITY;
        for (int jj = lane; jj < c; jj += 64) m = fmaxf(m, wts[wv][jj]);
        m = wr_max(m);
        float l = 0.f;
        for (int jj = lane; jj < c; jj += 64) { float t = expf(wts[wv][jj] - m); wts[wv][jj] = t; l += t; }
        l = wr_sum(l);
        if (lane == 0) lsum[wv] = l;
    }
    __syncthreads();
    int hq = lane >> 4;
    const float4* hvv = (const float4*)h2;
    float4 acc = {0.f, 0.f, 0.f, 0.f};
    int jj = wv;
    for (; jj + 12 < c; jj += 16) {
        int na = nbrs[jj], nb = nbrs[jj + 4], nc = nbrs[jj + 8], nd = nbrs[jj + 12];
        float wa = wts[hq][jj], wb = wts[hq][jj + 4], wc = wts[hq][jj + 8], wd = wts[hq][jj + 12];
        float4 va = hvv[(size_t)na * 64 + lane];
        float4 vb = hvv[(size_t)nb * 64 + lane];
        float4 vc = hvv[(size_t)nc * 64 + lane];
        float4 vd = hvv[(size_t)nd * 64 + lane];
        acc.x = fmaf(wa, va.x, acc.x); acc.y = fmaf(wa, va.y, acc.y);
        acc.z = fmaf(wa, va.z, acc.z); acc.w = fmaf(wa, va.w, acc.w);
        acc.x = fmaf(wb, vb.x, acc.x); acc.y = fmaf(wb, vb.y, acc.y);
        acc.z = fmaf(wb, vb.z, acc.z); acc.w = fmaf(wb, vb.w, acc.w);
        acc.x = fmaf(wc, vc.x, acc.x); acc.y = fmaf(wc, vc.y, acc.y);
        acc.z = fmaf(wc, vc.z, acc.z); acc.w = fmaf(wc, vc.w, acc.w);
        acc.x = fmaf(wd, vd.x, acc.x); acc.y = fmaf(wd, vd.y, acc.y);
        acc.z = fmaf(wd, vd.z, acc.z); acc.w = fmaf(wd, vd.w, acc.w);
    }
    for (; jj < c; jj += 4) {
        int na = nbrs[jj];
        float wa = wts[hq][jj];
        float4 va = hvv[(size_t)na * 64 + lane];
        acc.x = fmaf(wa, va.x, acc.x); acc.y = fmaf(wa, va.y, acc.y);
        acc.z = fmaf(wa, va.z, acc.z); acc.w = fmaf(wa, va.w, acc.w);
    }
    ((float4*)&sacc[wv][0])[lane] = acc;
    __syncthreads();
    if (wv == 0) {
        float t0 = 0.f, t1 = 0.f, t2 = 0.f, t3 = 0.f;
#pragma unroll
        for (int w = 0; w < 4; ++w) {
            t0 += sacc[w][lane];
            t1 += sacc[w][lane + 64];
            t2 += sacc[w][lane + 128];
            t3 += sacc[w][lane + 192];
        }
        float mv = (t0 / lsum[0] + t1 / lsum[1] + t2 / lsum[2] + t3 / lsum[3]) * 0.25f;
        float mu = wr_sum(mv) * (1.f / HID);
        float dvv = mv - mu;
        float var = wr_sum(dvv * dvv) * (1.f / HID);
        float y = dvv * rsqrtf(var + 1e-5f) * g[lane] + b[lane];
        xo[i * HID + lane] = y > 0.f ? y : expm1f(y);
    }
}

// ---------------- fused clause pooling + scorer ----------------
__global__ __launch_bounds__(256) void k_poolscore(const float* __restrict__ pm, const float* __restrict__ x2,
                                                   const float* __restrict__ Ws, const float* __restrict__ bs,
                                                   const float* __restrict__ Wo, const float* __restrict__ bo,
                                                   float* __restrict__ out) {
    int c = blockIdx.x, tid = threadIdx.x;
    int w = tid >> 6, lane = tid & 63;
    __shared__ float sacc[4][HID];
    __shared__ float ce_s[HID];
    float acc = 0.f;
    const float4* pmv = (const float4*)(pm + (size_t)c * N);
#pragma unroll
    for (int it = 0; it < 4; ++it) {
        int vi = w * 256 + it * 64 + lane;   // float4 index into the pm row
        float4 p4 = pmv[vi];
        float pc[4] = {p4.x, p4.y, p4.z, p4.w};
#pragma unroll
        for (int comp = 0; comp < 4; ++comp) {
            unsigned long long msk = __ballot(pc[comp] != 0.f);
            while (msk) {
                int bpos = __ffsll(msk) - 1;
                msk &= msk - 1;
                float pj = __shfl(pc[comp], bpos);
                int j = (w * 256 + it * 64 + bpos) * 4 + comp;
                acc += pj * x2[(size_t)j * HID + lane];
            }
        }
    }
    sacc[w][lane] = acc;
    __syncthreads();
    if (w == 0) ce_s[lane] = sacc[0][lane] + sacc[1][lane] + sacc[2][lane] + sacc[3][lane];
    __syncthreads();
    if (w == 0) {
        float hd = bs[lane];
#pragma unroll 8
        for (int k = 0; k < HID; ++k) hd = fmaf(ce_s[k], Ws[k * HID + lane], hd);
        hd = fmaxf(hd, 0.f);
        float v = wr_sum(hd * Wo[lane]);
        if (lane == 0) out[c] = v + bo[0];
    }
}

extern "C" void kernel_launch(void* const* d_in, const int* in_sizes, int n_in,
                              void* d_out, int out_size, void* d_ws, size_t ws_size,
                              hipStream_t stream) {
    const float* nf  = (const float*)d_in[0];
    const float* adj = (const float*)d_in[1];
    const float* pm  = (const float*)d_in[2];
    const float* W1  = (const float*)d_in[3];
    const float* as1 = (const float*)d_in[4];
    const float* ad1 = (const float*)d_in[5];
    const float* g1  = (const float*)d_in[6];
    const float* b1  = (const float*)d_in[7];
    const float* W2  = (const float*)d_in[8];
    const float* as2 = (const float*)d_in[9];
    const float* ad2 = (const float*)d_in[10];
    const float* g2  = (const float*)d_in[11];
    const float* b2  = (const float*)d_in[12];
    const float* Ws  = (const float*)d_in[13];
    const float* bs  = (const float*)d_in[14];
    const float* Wo  = (const float*)d_in[15];
    const float* bo  = (const float*)d_in[16];
    float* out = (float*)d_out;

    float* p = (float*)d_ws;
    float* h1  = p; p += (size_t)N * F1;
    float* s1  = p; p += (size_t)N * HEADS;
    float* d1  = p; p += (size_t)N * HEADS;
    float* x1  = p; p += (size_t)N * F1;
    float* h2  = p; p += (size_t)N * F1;
    float* s2  = p; p += (size_t)N * HEADS;
    float* d2  = p; p += (size_t)N * HEADS;
    float* x2  = p; p += (size_t)N * HID;
    int* cnt = (int*)p;
    int* idx = cnt + N;

    k_build<<<N, 256, 0, stream>>>(adj, cnt, idx);
    k_gemm1<<<N / RPB, 256, 0, stream>>>(nf, W1, as1, ad1, h1, s1, d1);
    k_agg1<<<N, 256, 0, stream>>>(h1, s1, d1, cnt, idx, g1, b1, x1);
    k_gemm2<<<N / RPB, 256, 0, stream>>>(x1, W2, as2, ad2, h2, s2, d2);
    k_agg2<<<N, 256, 0, stream>>>(h2, s2, d2, cnt, idx, g2, b2, x2);
    k_poolscore<<<C, 256, 0, stream>>>(pm, x2, Ws, bs, Wo, bo, out);
}